// Round 5
// baseline (457.010 us; speedup 1.0000x reference)
//
#include <hip/hip_runtime.h>
#include <math.h>

#define NUM_CODES 1024
#define DIM 64
#define HW 1024
#define NPTS 65536
#define PTS 128           // points per block
#define CAP 8
#define W_WINDOW 1.5e-3f  // covers hh-only score error (bound ~8e-4, realistic ~4e-5)

using short8 = __attribute__((ext_vector_type(8))) short;
using f32x4  = __attribute__((ext_vector_type(4))) float;

// ---- numpy-exact helpers (verified rounds 2-4: absmax 0.0) ----
__device__ __forceinline__ float pairwise_sumsq64(const float* v) {
    float r[8];
#pragma unroll
    for (int j = 0; j < 8; ++j) r[j] = __fmul_rn(v[j], v[j]);
#pragma unroll
    for (int i = 8; i < 64; i += 8) {
#pragma unroll
        for (int j = 0; j < 8; ++j)
            r[j] = __fadd_rn(r[j], __fmul_rn(v[i + j], v[i + j]));
    }
    return __fadd_rn(
        __fadd_rn(__fadd_rn(r[0], r[1]), __fadd_rn(r[2], r[3])),
        __fadd_rn(__fadd_rn(r[4], r[5]), __fadd_rn(r[6], r[7])));
}

__device__ __forceinline__ float replica_d(const float* x, const float* wr,
                                           float t1, float t3k) {
    float acc = 0.0f;
#pragma unroll
    for (int j = 0; j < 64; ++j) acc = __fmaf_rn(x[j], wr[j], acc);
    return __fadd_rn(__fsub_rn(t1, __fmul_rn(2.0f, acc)), t3k);
}

__device__ __forceinline__ unsigned short bf16_rne(float v) {
    unsigned int u = __float_as_uint(v);
    return (unsigned short)((u + 0x7fffu + ((u >> 16) & 1u)) >> 16);
}

// ---- Kernel 0: prep  w_hi (bf16) + t3 (numpy-exact) ----
__global__ void vq_prep_kernel(const float* __restrict__ w,
                               unsigned short* __restrict__ whi,
                               float* __restrict__ t3) {
    int k = blockIdx.x * blockDim.x + threadIdx.x;
    if (k >= NUM_CODES) return;
    float row[64];
#pragma unroll
    for (int j = 0; j < 64; ++j) row[j] = w[k * DIM + j];
    t3[k] = pairwise_sumsq64(row);
#pragma unroll
    for (int j = 0; j < 64; ++j) whi[k * DIM + j] = bf16_rne(row[j]);
}

// ---- Kernel 1: main. Block = 512 thr = 8 waves; 128 points.
// Code-split: wave wv handles ALL 8 point-tiles x codes [wv*128, wv*128+128).
__global__ __launch_bounds__(512, 4) void vq_main_kernel(
        const float* __restrict__ z,
        const float* __restrict__ w,
        const unsigned short* __restrict__ whi,
        const float* __restrict__ t3,
        float* __restrict__ out) {
    __shared__ __align__(16) unsigned short s_xhi[PTS * 72];
    __shared__ float s_pmin[8][PTS];
    __shared__ float s_thr[PTS];
    __shared__ int s_list[PTS * CAP];
    __shared__ int s_cnt[PTS];
    __shared__ int s_best[PTS];

    const int tid = threadIdx.x;
    const int lane = tid & 63;
    const int wv = tid >> 6;          // 0..7
    const int n0 = blockIdx.x * PTS;
    const int b = n0 >> 10;
    const int hw0 = n0 & (HW - 1);

    if (tid < PTS) s_cnt[tid] = 0;

    // stage 128 points as bf16-hi into LDS; coalesced 128-wide global reads
    {
        int hw_off = tid & 127;
        int dbase = tid >> 7;         // 0..3
#pragma unroll
        for (int i = 0; i < 16; ++i) {
            int d = dbase + i * 4;
            float v = z[((size_t)(b * 64 + d)) * HW + hw0 + hw_off];
            s_xhi[hw_off * 72 + d] = bf16_rne(v);
        }
    }
    __syncthreads();

    const int col = lane & 15;
    const int q = lane >> 4;

    // A fragments for all 8 point-tiles (hi only)
    short8 ah0[8], ah1[8];
#pragma unroll
    for (int at = 0; at < 8; ++at) {
        int arow = at * 16 + col;
        ah0[at] = *(const short8*)&s_xhi[arow * 72 + q * 8];
        ah1[at] = *(const short8*)&s_xhi[arow * 72 + 32 + q * 8];
    }

    const int T0 = wv * 8;

    // ---- pass 1: per-point min over this wave's 128 codes ----
    float s1[8][4];
#pragma unroll
    for (int at = 0; at < 8; ++at)
#pragma unroll
        for (int r = 0; r < 4; ++r) s1[at][r] = INFINITY;

#pragma unroll 2
    for (int t = 0; t < 8; ++t) {
        int code = (T0 + t) * 16 + col;
        short8 b0 = *(const short8*)(whi + code * 64 + q * 8);
        short8 b1 = *(const short8*)(whi + code * 64 + 32 + q * 8);
        float t3v = t3[code];
#pragma unroll
        for (int at = 0; at < 8; ++at) {
            f32x4 c = {0.f, 0.f, 0.f, 0.f};
            c = __builtin_amdgcn_mfma_f32_16x16x32_bf16(ah0[at], b0, c, 0, 0, 0);
            c = __builtin_amdgcn_mfma_f32_16x16x32_bf16(ah1[at], b1, c, 0, 0, 0);
#pragma unroll
            for (int r = 0; r < 4; ++r)
                s1[at][r] = fminf(s1[at][r], fmaf(-2.0f, c[r], t3v));
        }
    }

    // reduce over the 16 lanes (col bits) sharing each point
#pragma unroll
    for (int mask = 1; mask <= 8; mask <<= 1)
#pragma unroll
        for (int at = 0; at < 8; ++at)
#pragma unroll
            for (int r = 0; r < 4; ++r)
                s1[at][r] = fminf(s1[at][r], __shfl_xor(s1[at][r], mask, 64));

    if (col == 0) {
#pragma unroll
        for (int at = 0; at < 8; ++at)
#pragma unroll
            for (int r = 0; r < 4; ++r)
                s_pmin[wv][at * 16 + q * 4 + r] = s1[at][r];
    }
    __syncthreads();

    if (tid < PTS) {
        float m = s_pmin[0][tid];
#pragma unroll
        for (int i = 1; i < 8; ++i) m = fminf(m, s_pmin[i][tid]);
        s_thr[tid] = m + W_WINDOW;
    }
    __syncthreads();

    float thr[8][4];
#pragma unroll
    for (int at = 0; at < 8; ++at)
#pragma unroll
        for (int r = 0; r < 4; ++r)
            thr[at][r] = s_thr[at * 16 + q * 4 + r];

    // ---- pass 2: recompute scores (bitwise-identical), collect candidates ----
#pragma unroll 2
    for (int t = 0; t < 8; ++t) {
        int code = (T0 + t) * 16 + col;
        short8 b0 = *(const short8*)(whi + code * 64 + q * 8);
        short8 b1 = *(const short8*)(whi + code * 64 + 32 + q * 8);
        float t3v = t3[code];
#pragma unroll
        for (int at = 0; at < 8; ++at) {
            f32x4 c = {0.f, 0.f, 0.f, 0.f};
            c = __builtin_amdgcn_mfma_f32_16x16x32_bf16(ah0[at], b0, c, 0, 0, 0);
            c = __builtin_amdgcn_mfma_f32_16x16x32_bf16(ah1[at], b1, c, 0, 0, 0);
#pragma unroll
            for (int r = 0; r < 4; ++r) {
                float s = fmaf(-2.0f, c[r], t3v);
                if (s <= thr[at][r]) {
                    int pt = at * 16 + q * 4 + r;
                    int idx = atomicAdd(&s_cnt[pt], 1);
                    if (idx < CAP) s_list[pt * CAP + idx] = code;
                }
            }
        }
    }
    __syncthreads();

    // ---- selection: exact fp32 replica among candidates (x from L2-hot z) ----
    if (tid < PTS) {
        int pt = tid;
        int m = s_cnt[pt];
        int best = s_list[pt * CAP];
        if (m > 1) {
            float x[64];
#pragma unroll
            for (int j = 0; j < 64; ++j)
                x[j] = z[((size_t)(b * 64 + j)) * HW + hw0 + pt];
            float t1 = pairwise_sumsq64(x);
            float dbest = INFINITY;
            if (m <= CAP) {
                int ks[CAP];
                for (int i = 0; i < m; ++i) ks[i] = s_list[pt * CAP + i];
                for (int i = 1; i < m; ++i) {          // sort ascending k
                    int key = ks[i]; int j2 = i - 1;
                    while (j2 >= 0 && ks[j2] > key) { ks[j2 + 1] = ks[j2]; --j2; }
                    ks[j2 + 1] = key;
                }
                for (int i = 0; i < m; ++i) {          // first-occurrence argmin
                    int k = ks[i];
                    float d = replica_d(x, w + (size_t)k * DIM, t1, t3[k]);
                    if (d < dbest) { dbest = d; best = k; }
                }
            } else {
                best = 0;                               // overflow guard: full scan
                for (int k = 0; k < NUM_CODES; ++k) {
                    float d = replica_d(x, w + (size_t)k * DIM, t1, t3[k]);
                    if (d < dbest) { dbest = d; best = k; }
                }
            }
        }
        s_best[pt] = best;
    }
    __syncthreads();

    // ---- output: out[b, c, hw0+pt] = w[best[pt]][c], coalesced 128-wide ----
    {
        int pt = tid & 127;
        int cb = tid >> 7;            // 0..3
        int bk = s_best[pt];
        const float* wrow = w + (size_t)bk * DIM;
#pragma unroll
        for (int i = 0; i < 16; ++i) {
            int c = cb + i * 4;
            out[((size_t)(b * 64 + c)) * HW + hw0 + pt] = wrow[c];
        }
    }
}

extern "C" void kernel_launch(void* const* d_in, const int* in_sizes, int n_in,
                              void* d_out, int out_size, void* d_ws, size_t ws_size,
                              hipStream_t stream) {
    const float* z = (const float*)d_in[0];
    const float* w = (const float*)d_in[1];
    float* out = (float*)d_out;

    unsigned short* whi = (unsigned short*)d_ws;        // 128 KB
    float* t3 = (float*)((char*)d_ws + 131072);         // 4 KB

    vq_prep_kernel<<<NUM_CODES / 256, 256, 0, stream>>>(w, whi, t3);
    vq_main_kernel<<<NPTS / PTS, 512, 0, stream>>>(z, w, whi, t3, out);
}

// Round 6
// 387.291 us; speedup vs baseline: 1.1800x; 1.1800x over previous
//
#include <hip/hip_runtime.h>
#include <math.h>

#define NUM_CODES 1024
#define DIM 64
#define HW 1024
#define NPTS 65536
#define PTS 128            // points per block
#define CAP 8
#define W_WINDOW 1.5e-3f   // validated round 5 with hh-only scores (absmax 0)

using short8 = __attribute__((ext_vector_type(8))) short;
using f32x4  = __attribute__((ext_vector_type(4))) float;

// ---- numpy-exact helpers (verified rounds 2-5: absmax 0.0) ----
__device__ __forceinline__ float pairwise_sumsq64(const float* v) {
    float r[8];
#pragma unroll
    for (int j = 0; j < 8; ++j) r[j] = __fmul_rn(v[j], v[j]);
#pragma unroll
    for (int i = 8; i < 64; i += 8) {
#pragma unroll
        for (int j = 0; j < 8; ++j)
            r[j] = __fadd_rn(r[j], __fmul_rn(v[i + j], v[i + j]));
    }
    return __fadd_rn(
        __fadd_rn(__fadd_rn(r[0], r[1]), __fadd_rn(r[2], r[3])),
        __fadd_rn(__fadd_rn(r[4], r[5]), __fadd_rn(r[6], r[7])));
}

__device__ __forceinline__ float replica_d(const float* x, const float* wr,
                                           float t1, float t3k) {
    float acc = 0.0f;
#pragma unroll
    for (int j = 0; j < 64; ++j) acc = __fmaf_rn(x[j], wr[j], acc);
    return __fadd_rn(__fsub_rn(t1, __fmul_rn(2.0f, acc)), t3k);
}

__device__ __forceinline__ unsigned short bf16_rne(float v) {
    unsigned int u = __float_as_uint(v);
    return (unsigned short)((u + 0x7fffu + ((u >> 16) & 1u)) >> 16);
}

// ---- Kernel 0: prep  w_hi (bf16) + t3 (numpy-exact) ----
__global__ void vq_prep_kernel(const float* __restrict__ w,
                               unsigned short* __restrict__ whi,
                               float* __restrict__ t3) {
    int k = blockIdx.x * blockDim.x + threadIdx.x;
    if (k >= NUM_CODES) return;
    float row[64];
#pragma unroll
    for (int j = 0; j < 64; ++j) row[j] = w[k * DIM + j];
    t3[k] = pairwise_sumsq64(row);
#pragma unroll
    for (int j = 0; j < 64; ++j) whi[k * DIM + j] = bf16_rne(row[j]);
}

// ---- Kernel 1: main ----
// Block = 512 thr = 8 waves; 128 points (8 point-tiles).
// Wave w: at-group g=w>>2 owns point-tiles [4g,4g+4); code-lane cl=w&3 owns
// code-tiles [2cl, 2cl+2) of each staged 128-code chunk. 8 chunks, dbuf LDS.
__global__ __launch_bounds__(512, 2) void vq_main_kernel(
        const float* __restrict__ z,
        const float* __restrict__ w,
        const unsigned short* __restrict__ whi,
        const float* __restrict__ t3,
        float* __restrict__ out) {
    __shared__ __align__(16) unsigned short s_xhi[PTS * 72];      // 18.4 KB
    __shared__ __align__(16) unsigned short s_b[2][128 * 72];     // 36.9 KB
    __shared__ float s_pmin[8][PTS];
    __shared__ float s_thr[PTS];
    __shared__ int s_list[PTS * CAP];
    __shared__ int s_cnt[PTS];
    __shared__ int s_best[PTS];

    const int tid = threadIdx.x;
    const int lane = tid & 63;
    const int wv = tid >> 6;           // 0..7
    const int g = wv >> 2;             // at-group 0/1
    const int cl = wv & 3;             // code-lane 0..3
    const int n0 = blockIdx.x * PTS;
    const int b = n0 >> 10;
    const int hw0 = n0 & (HW - 1);

    if (tid < PTS) s_cnt[tid] = 0;

    // stage 128 points as bf16-hi into LDS; coalesced 128-wide global reads
    {
        int hw_off = tid & 127;
        int dbase = tid >> 7;          // 0..3
#pragma unroll
        for (int i = 0; i < 16; ++i) {
            int d = dbase + i * 4;
            float v = z[((size_t)(b * 64 + d)) * HW + hw0 + hw_off];
            s_xhi[hw_off * 72 + d] = bf16_rne(v);
        }
    }
    __syncthreads();

    const int col = lane & 15;
    const int q = lane >> 4;

    // A fragments for this wave's 4 point-tiles
    short8 ah0[4], ah1[4];
#pragma unroll
    for (int at = 0; at < 4; ++at) {
        int arow = (g * 4 + at) * 16 + col;
        ah0[at] = *(const short8*)&s_xhi[arow * 72 + q * 8];
        ah1[at] = *(const short8*)&s_xhi[arow * 72 + 32 + q * 8];
    }

    // staging geometry: chunk = 128 codes x 64 bf16 = 1024 segs of 16B;
    // thread handles segs tid and tid+512. seg s: row=s>>3, off=(s&7)*8 elems.
    const int sg0 = tid, sg1 = tid + 512;
    const int r0 = sg0 >> 3, o0 = (sg0 & 7) * 8;
    const int r1 = sg1 >> 3, o1 = (sg1 & 7) * 8;

#define STAGE_LOAD(c, v0, v1)                                                  \
    v0 = *(const short8*)(whi + ((size_t)((c)*128 + r0)) * 64 + o0);           \
    v1 = *(const short8*)(whi + ((size_t)((c)*128 + r1)) * 64 + o1);

#define STAGE_WRITE(buf, v0, v1)                                               \
    *(short8*)&s_b[buf][r0 * 72 + o0] = v0;                                    \
    *(short8*)&s_b[buf][r1 * 72 + o1] = v1;

    // per-point running scores
    float s1[4][4];
    float thr[4][4];

    // ================= PASS 1: min score =================
#pragma unroll
    for (int at = 0; at < 4; ++at)
#pragma unroll
        for (int r = 0; r < 4; ++r) s1[at][r] = INFINITY;

    {
        short8 v0, v1;
        STAGE_LOAD(0, v0, v1);
        STAGE_WRITE(0, v0, v1);
        __syncthreads();
        for (int c = 0; c < 8; ++c) {
            int buf = c & 1;
            short8 n0r, n1r;
            if (c < 7) { STAGE_LOAD(c + 1, n0r, n1r); }   // issue early
#pragma unroll
            for (int t = 0; t < 2; ++t) {
                int lrow = (cl * 2 + t) * 16 + col;
                short8 b0 = *(const short8*)&s_b[buf][lrow * 72 + q * 8];
                short8 b1 = *(const short8*)&s_b[buf][lrow * 72 + 32 + q * 8];
                float t3v = t3[c * 128 + lrow];
#pragma unroll
                for (int at = 0; at < 4; ++at) {
                    f32x4 cc = {0.f, 0.f, 0.f, 0.f};
                    cc = __builtin_amdgcn_mfma_f32_16x16x32_bf16(ah0[at], b0, cc, 0, 0, 0);
                    cc = __builtin_amdgcn_mfma_f32_16x16x32_bf16(ah1[at], b1, cc, 0, 0, 0);
#pragma unroll
                    for (int r = 0; r < 4; ++r)
                        s1[at][r] = fminf(s1[at][r], fmaf(-2.0f, cc[r], t3v));
                }
            }
            if (c < 7) { STAGE_WRITE(!buf, n0r, n1r); }
            __syncthreads();
        }
    }

    // reduce over 16 col-lanes sharing each point
#pragma unroll
    for (int mask = 1; mask <= 8; mask <<= 1)
#pragma unroll
        for (int at = 0; at < 4; ++at)
#pragma unroll
            for (int r = 0; r < 4; ++r)
                s1[at][r] = fminf(s1[at][r], __shfl_xor(s1[at][r], mask, 64));

    if (col == 0) {
#pragma unroll
        for (int at = 0; at < 4; ++at)
#pragma unroll
            for (int r = 0; r < 4; ++r)
                s_pmin[wv][(g * 4 + at) * 16 + q * 4 + r] = s1[at][r];
    }
    __syncthreads();

    if (tid < PTS) {
        int gg = tid >> 6;             // point's at-group
        float m = s_pmin[gg * 4 + 0][tid];
#pragma unroll
        for (int i = 1; i < 4; ++i) m = fminf(m, s_pmin[gg * 4 + i][tid]);
        s_thr[tid] = m + W_WINDOW;
    }
    __syncthreads();

#pragma unroll
    for (int at = 0; at < 4; ++at)
#pragma unroll
        for (int r = 0; r < 4; ++r)
            thr[at][r] = s_thr[(g * 4 + at) * 16 + q * 4 + r];

    // ================= PASS 2: collect candidates =================
    {
        short8 v0, v1;
        STAGE_LOAD(0, v0, v1);
        STAGE_WRITE(0, v0, v1);
        __syncthreads();
        for (int c = 0; c < 8; ++c) {
            int buf = c & 1;
            short8 n0r, n1r;
            if (c < 7) { STAGE_LOAD(c + 1, n0r, n1r); }
#pragma unroll
            for (int t = 0; t < 2; ++t) {
                int lrow = (cl * 2 + t) * 16 + col;
                short8 b0 = *(const short8*)&s_b[buf][lrow * 72 + q * 8];
                short8 b1 = *(const short8*)&s_b[buf][lrow * 72 + 32 + q * 8];
                float t3v = t3[c * 128 + lrow];
#pragma unroll
                for (int at = 0; at < 4; ++at) {
                    f32x4 cc = {0.f, 0.f, 0.f, 0.f};
                    cc = __builtin_amdgcn_mfma_f32_16x16x32_bf16(ah0[at], b0, cc, 0, 0, 0);
                    cc = __builtin_amdgcn_mfma_f32_16x16x32_bf16(ah1[at], b1, cc, 0, 0, 0);
#pragma unroll
                    for (int r = 0; r < 4; ++r) {
                        float s = fmaf(-2.0f, cc[r], t3v);
                        if (s <= thr[at][r]) {
                            int pt = (g * 4 + at) * 16 + q * 4 + r;
                            int idx = atomicAdd(&s_cnt[pt], 1);
                            if (idx < CAP) s_list[pt * CAP + idx] = c * 128 + lrow;
                        }
                    }
                }
            }
            if (c < 7) { STAGE_WRITE(!buf, n0r, n1r); }
            __syncthreads();
        }
    }

    // ---- selection: exact fp32 replica among candidates (x from L2-hot z) ----
    if (tid < PTS) {
        int pt = tid;
        int m = s_cnt[pt];
        int best = s_list[pt * CAP];
        if (m > 1) {
            float x[64];
#pragma unroll
            for (int j = 0; j < 64; ++j)
                x[j] = z[((size_t)(b * 64 + j)) * HW + hw0 + pt];
            float t1 = pairwise_sumsq64(x);
            float dbest = INFINITY;
            if (m <= CAP) {
                int ks[CAP];
                for (int i = 0; i < m; ++i) ks[i] = s_list[pt * CAP + i];
                for (int i = 1; i < m; ++i) {           // sort ascending k
                    int key = ks[i]; int j2 = i - 1;
                    while (j2 >= 0 && ks[j2] > key) { ks[j2 + 1] = ks[j2]; --j2; }
                    ks[j2 + 1] = key;
                }
                for (int i = 0; i < m; ++i) {           // first-occurrence argmin
                    int k = ks[i];
                    float d = replica_d(x, w + (size_t)k * DIM, t1, t3[k]);
                    if (d < dbest) { dbest = d; best = k; }
                }
            } else {
                best = 0;                               // overflow guard: full scan
                for (int k = 0; k < NUM_CODES; ++k) {
                    float d = replica_d(x, w + (size_t)k * DIM, t1, t3[k]);
                    if (d < dbest) { dbest = d; best = k; }
                }
            }
        }
        s_best[pt] = best;
    }
    __syncthreads();

    // ---- output: out[b, c, hw0+pt] = w[best[pt]][c], coalesced 128-wide ----
    {
        int pt = tid & 127;
        int cb = tid >> 7;             // 0..3
        int bk = s_best[pt];
        const float* wrow = w + (size_t)bk * DIM;
#pragma unroll
        for (int i = 0; i < 16; ++i) {
            int c = cb + i * 4;
            out[((size_t)(b * 64 + c)) * HW + hw0 + pt] = wrow[c];
        }
    }
#undef STAGE_LOAD
#undef STAGE_WRITE
}

extern "C" void kernel_launch(void* const* d_in, const int* in_sizes, int n_in,
                              void* d_out, int out_size, void* d_ws, size_t ws_size,
                              hipStream_t stream) {
    const float* z = (const float*)d_in[0];
    const float* w = (const float*)d_in[1];
    float* out = (float*)d_out;

    unsigned short* whi = (unsigned short*)d_ws;        // 128 KB
    float* t3 = (float*)((char*)d_ws + 131072);         // 4 KB

    vq_prep_kernel<<<NUM_CODES / 256, 256, 0, stream>>>(w, whi, t3);
    vq_main_kernel<<<NPTS / PTS, 512, 0, stream>>>(z, w, whi, t3, out);
}